// Round 1
// baseline (422.560 us; speedup 1.0000x reference)
//
#include <hip/hip_runtime.h>
#include <hip/hip_bf16.h>

// B=8, S=2048, DMODEL=1024, DK=128
#define SEQ 2048
#define DMODEL 1024
#define DK 128

typedef __bf16 bf16x8 __attribute__((ext_vector_type(8)));
typedef float  f32x4  __attribute__((ext_vector_type(4)));

#define L2E 1.44269504088896340736f

// ---------------- workspace element offsets (bf16 elements) ----------------
// wpack: [p][hi/lo][128][1024]  -> p*262144 (+131072 for lo)
// q:  [16384][128]  at 786432
// k:  [16384][128]  at 2883584
// vt: [8][128][2048] at 4980736
#define WS_Q  786432
#define WS_K  2883584
#define WS_VT 4980736

// ---------------------------------------------------------------------------
// Kernel 1: convert Wq/Wk/Wv fp32 -> split bf16 (hi + lo). Scale folded in Wq.
// ---------------------------------------------------------------------------
__global__ __launch_bounds__(256) void wconv_kernel(
    const float* __restrict__ wq, const float* __restrict__ wk,
    const float* __restrict__ wv, __bf16* __restrict__ wpack)
{
    int i = blockIdx.x * 256 + threadIdx.x;     // 0 .. 393215
    int p = i >> 17;                            // 131072 = 2^17 elems per W
    int j = i & 131071;
    const float* src = (p == 0) ? wq : ((p == 1) ? wk : wv);
    float f = src[j];
    if (p == 0) f *= 0.08838834764831845f;      // 1/sqrt(128) folded into Wq
    __bf16 h = (__bf16)f;
    __bf16 l = (__bf16)(f - (float)h);
    wpack[p * 262144 + j]          = h;
    wpack[p * 262144 + 131072 + j] = l;
}

// ---------------------------------------------------------------------------
// Kernel 2: projection GEMM.  out[m][n] = sum_k x[m][k] * W[n][k]
// Split-bf16: x->(xh,xl), W->(wh,wl); acc += xh*wh + xl*wh + xh*wl.
// Block: 128 rows x 128 cols, 4 waves (waveM=32 via 2 m-tiles of 16).
// A loaded global->regs (fp32, converted in-flight); W hi/lo staged in LDS.
// p=0 -> q[s][d], p=1 -> k[s][d], p=2 -> v stored transposed vt[d][s].
// ---------------------------------------------------------------------------
__global__ __launch_bounds__(256) void proj_kernel(
    const float* __restrict__ xq, const float* __restrict__ xk,
    const float* __restrict__ xv, const __bf16* __restrict__ wpack,
    __bf16* __restrict__ qws, __bf16* __restrict__ kws, __bf16* __restrict__ vtws)
{
    const int p = blockIdx.y;
    const float* __restrict__ x = (p == 0) ? xq : ((p == 1) ? xk : xv);
    const __bf16* __restrict__ whi_g = wpack + p * 262144;
    const __bf16* __restrict__ wlo_g = whi_g + 131072;

    const int mtile = blockIdx.x;
    const int m0 = mtile << 7;                  // 128 rows/block
    const int t = threadIdx.x;
    const int wv_ = t >> 6;
    const int lane = t & 63;
    const int l15 = lane & 15, g = lane >> 4;

    // LDS: whi[128][72], wlo[128][72]  (pad +8 bf16 -> bank-uniform b128 reads)
    __shared__ __align__(16) __bf16 smem[18432];
    __bf16* whl = smem;
    __bf16* wll = smem + 9216;

    f32x4 acc[2][8];
    for (int mt = 0; mt < 2; ++mt)
        for (int nt = 0; nt < 8; ++nt) acc[mt][nt] = (f32x4){0.f, 0.f, 0.f, 0.f};

    for (int kk = 0; kk < 16; ++kk) {           // BK = 64
        __syncthreads();
        // stage W hi/lo tiles: 2 x (128 rows x 64 cols) bf16 = 2048 16B chunks
#pragma unroll
        for (int i = 0; i < 8; ++i) {
            int idx = i * 256 + t;
            int h = idx >> 10, rem = idx & 1023;
            int row = rem >> 3, ck = rem & 7;
            const __bf16* src = (h ? wlo_g : whi_g) + row * 1024 + kk * 64 + ck * 8;
            __bf16* dst = (h ? wll : whl) + row * 72 + ck * 8;
            *(bf16x8*)dst = *(const bf16x8*)src;
        }
        __syncthreads();

        for (int ks = 0; ks < 2; ++ks) {
            bf16x8 ah[2], al[2];
#pragma unroll
            for (int mt = 0; mt < 2; ++mt) {
                int row = m0 + wv_ * 32 + mt * 16 + l15;
                int col = kk * 64 + ks * 32 + g * 8;
                const float* xp = x + row * 1024 + col;
                f32x4 a0 = *(const f32x4*)xp;
                f32x4 a1 = *(const f32x4*)(xp + 4);
#pragma unroll
                for (int j = 0; j < 4; ++j) {
                    __bf16 h0 = (__bf16)a0[j];
                    ah[mt][j] = h0; al[mt][j] = (__bf16)(a0[j] - (float)h0);
                    __bf16 h1 = (__bf16)a1[j];
                    ah[mt][4 + j] = h1; al[mt][4 + j] = (__bf16)(a1[j] - (float)h1);
                }
            }
#pragma unroll
            for (int nt = 0; nt < 8; ++nt) {
                const __bf16* bp = whl + (nt * 16 + l15) * 72 + ks * 32 + g * 8;
                bf16x8 bh = *(const bf16x8*)bp;
                bf16x8 bl = *(const bf16x8*)(bp + 9216);
#pragma unroll
                for (int mt = 0; mt < 2; ++mt) {
                    acc[mt][nt] = __builtin_amdgcn_mfma_f32_16x16x32_bf16(ah[mt], bh, acc[mt][nt], 0, 0, 0);
                    acc[mt][nt] = __builtin_amdgcn_mfma_f32_16x16x32_bf16(al[mt], bh, acc[mt][nt], 0, 0, 0);
                    acc[mt][nt] = __builtin_amdgcn_mfma_f32_16x16x32_bf16(ah[mt], bl, acc[mt][nt], 0, 0, 0);
                }
            }
        }
    }

    // epilogue: C frags -> LDS (transposed for p==2) -> coalesced bf16x8 stores
    __syncthreads();
    __bf16* olds = smem;                        // [128][136]
#pragma unroll
    for (int mt = 0; mt < 2; ++mt)
#pragma unroll
        for (int nt = 0; nt < 8; ++nt)
#pragma unroll
            for (int r = 0; r < 4; ++r) {
                int rowl = wv_ * 32 + mt * 16 + g * 4 + r;   // C row = (lane>>4)*4 + reg
                int col = nt * 16 + l15;                     // C col = lane&15
                __bf16 v = (__bf16)acc[mt][nt][r];
                if (p < 2) olds[rowl * 136 + col] = v;
                else       olds[col * 136 + rowl] = v;       // transpose for vt
            }
    __syncthreads();

    const int bq = mtile >> 4, s0 = (mtile & 15) << 7;
#pragma unroll
    for (int i = 0; i < 8; ++i) {
        int idx = i * 256 + t;
        int row = idx >> 4, ck = idx & 15;
        bf16x8 v = *(const bf16x8*)(olds + row * 136 + ck * 8);
        __bf16* dst;
        if (p == 0)      dst = qws + (m0 + row) * 128 + ck * 8;
        else if (p == 1) dst = kws + (m0 + row) * 128 + ck * 8;
        else             dst = vtws + ((size_t)(bq * 128 + row)) * 2048 + s0 + ck * 8;
        *(bf16x8*)dst = v;
    }
}

// ---------------------------------------------------------------------------
// Kernel 3: flash attention.  BLOCK_M=64 (4 waves x 16 rows), BLOCK_N=64.
// Online softmax; mask applied multiplicatively after exp (exact vs -1e9 ref).
// grid = 256; bb = blockIdx.x & 7 pins one batch per XCD (L2 locality).
// ---------------------------------------------------------------------------
__global__ __launch_bounds__(256) void flash_kernel(
    const __bf16* __restrict__ qws, const __bf16* __restrict__ kws,
    const __bf16* __restrict__ vtws, const int* __restrict__ mask,
    float* __restrict__ out)
{
    const int bb = blockIdx.x & 7;
    const int mtile = blockIdx.x >> 3;
    const int sq0 = mtile << 6;
    const int t = threadIdx.x;
    const int wv_ = t >> 6;
    const int lane = t & 63;
    const int l15 = lane & 15, g = lane >> 4;

    // LDS: k[64][136] (8704) | vt[128][72] (9216) | p[4 waves][16][72] (4608)
    __shared__ __align__(16) __bf16 smem[22528];
    __bf16* klds = smem;
    __bf16* vtlds = smem + 8704;
    __bf16* plds = smem + 17920 + wv_ * 1152;   // wave-private

    // Q fragments (A-layout, registers, pre-scaled by 1/sqrt(dk) via Wq)
    bf16x8 qf[4];
    {
        const __bf16* qp = qws + ((size_t)(bb * 2048 + sq0 + wv_ * 16 + l15)) * 128 + g * 8;
#pragma unroll
        for (int ks = 0; ks < 4; ++ks) qf[ks] = *(const bf16x8*)(qp + ks * 32);
    }

    f32x4 o[8];
#pragma unroll
    for (int nt = 0; nt < 8; ++nt) o[nt] = (f32x4){0.f, 0.f, 0.f, 0.f};
    float m_run[4], l_run[4];
#pragma unroll
    for (int r = 0; r < 4; ++r) { m_run[r] = -__builtin_inff(); l_run[r] = 0.f; }

    const int* mbase = mask + ((size_t)(bb * 2048 + sq0 + wv_ * 16 + g * 4)) * 2048 + l15;

    for (int kt = 0; kt < 32; ++kt) {
        const int n0 = kt << 6;
        __syncthreads();
        // stage K tile [64][128] and Vt tile [128][64] (bf16, padded rows)
#pragma unroll
        for (int i = 0; i < 8; ++i) {
            int idx = i * 256 + t;
            if (idx < 1024) {
                int row = idx >> 4, ck = idx & 15;
                *(bf16x8*)(klds + row * 136 + ck * 8) =
                    *(const bf16x8*)(kws + ((size_t)(bb * 2048 + n0 + row)) * 128 + ck * 8);
            } else {
                int v = idx - 1024;
                int row = v >> 3, ck = v & 7;
                *(bf16x8*)(vtlds + row * 72 + ck * 8) =
                    *(const bf16x8*)(vtws + ((size_t)(bb * 128 + row)) * 2048 + n0 + ck * 8);
            }
        }
        __syncthreads();

        // mask prefetch (in flight during QK MFMAs)
        int mv[4][4];
#pragma unroll
        for (int nt = 0; nt < 4; ++nt)
#pragma unroll
            for (int r = 0; r < 4; ++r)
                mv[nt][r] = mbase[(size_t)r * 2048 + n0 + nt * 16];

        // S = Q K^T  (pre-scaled)
        f32x4 sf[4];
#pragma unroll
        for (int nt = 0; nt < 4; ++nt) sf[nt] = (f32x4){0.f, 0.f, 0.f, 0.f};
#pragma unroll
        for (int nt = 0; nt < 4; ++nt) {
            const __bf16* kp = klds + (nt * 16 + l15) * 136 + g * 8;
#pragma unroll
            for (int ks = 0; ks < 4; ++ks) {
                bf16x8 bfk = *(const bf16x8*)(kp + ks * 32);
                sf[nt] = __builtin_amdgcn_mfma_f32_16x16x32_bf16(qf[ks], bfk, sf[nt], 0, 0, 0);
            }
        }

        // online softmax (rows: g*4+r, reduce across the 16 l15 lanes)
        float mx[4], mnew[4], alpha[4], psum[4];
#pragma unroll
        for (int r = 0; r < 4; ++r)
            mx[r] = fmaxf(fmaxf(sf[0][r], sf[1][r]), fmaxf(sf[2][r], sf[3][r]));
#pragma unroll
        for (int off = 1; off < 16; off <<= 1)
#pragma unroll
            for (int r = 0; r < 4; ++r)
                mx[r] = fmaxf(mx[r], __shfl_xor(mx[r], off, 64));
#pragma unroll
        for (int r = 0; r < 4; ++r) {
            mnew[r] = fmaxf(m_run[r], mx[r]);
            alpha[r] = exp2f((m_run[r] - mnew[r]) * L2E);
            psum[r] = 0.f;
        }
#pragma unroll
        for (int nt = 0; nt < 4; ++nt)
#pragma unroll
            for (int r = 0; r < 4; ++r) {
                float pv = exp2f((sf[nt][r] - mnew[r]) * L2E);
                pv = mv[nt][r] ? pv : 0.f;               // mask after exp: exact
                psum[r] += pv;
                plds[(g * 4 + r) * 72 + nt * 16 + l15] = (__bf16)pv;
            }
#pragma unroll
        for (int off = 1; off < 16; off <<= 1)
#pragma unroll
            for (int r = 0; r < 4; ++r)
                psum[r] += __shfl_xor(psum[r], off, 64);
#pragma unroll
        for (int r = 0; r < 4; ++r) {
            l_run[r] = l_run[r] * alpha[r] + psum[r];
            m_run[r] = mnew[r];
        }
#pragma unroll
        for (int nt = 0; nt < 8; ++nt)
#pragma unroll
            for (int r = 0; r < 4; ++r) o[nt][r] *= alpha[r];

        // P: C-layout -> A-layout via wave-private LDS
        bf16x8 pa[2];
#pragma unroll
        for (int ks2 = 0; ks2 < 2; ++ks2)
            pa[ks2] = *(const bf16x8*)(plds + l15 * 72 + ks2 * 32 + g * 8);

        // O += P V
#pragma unroll
        for (int nt2 = 0; nt2 < 8; ++nt2) {
            const __bf16* vp = vtlds + (nt2 * 16 + l15) * 72 + g * 8;
#pragma unroll
            for (int ks2 = 0; ks2 < 2; ++ks2) {
                bf16x8 bfv = *(const bf16x8*)(vp + ks2 * 32);
                o[nt2] = __builtin_amdgcn_mfma_f32_16x16x32_bf16(pa[ks2], bfv, o[nt2], 0, 0, 0);
            }
        }
    }

    // normalize + store fp32
    float inv[4];
#pragma unroll
    for (int r = 0; r < 4; ++r) inv[r] = 1.0f / l_run[r];
#pragma unroll
    for (int nt2 = 0; nt2 < 8; ++nt2)
#pragma unroll
        for (int r = 0; r < 4; ++r)
            out[((size_t)(bb * 2048 + sq0 + wv_ * 16 + g * 4 + r)) * 128 + nt2 * 16 + l15] =
                o[nt2][r] * inv[r];
}

// ---------------------------------------------------------------------------
extern "C" void kernel_launch(void* const* d_in, const int* in_sizes, int n_in,
                              void* d_out, int out_size, void* d_ws, size_t ws_size,
                              hipStream_t stream)
{
    const float* query = (const float*)d_in[0];
    const float* key   = (const float*)d_in[1];
    const float* value = (const float*)d_in[2];
    const int*   mask  = (const int*)d_in[3];
    const float* Wq    = (const float*)d_in[4];
    const float* Wk    = (const float*)d_in[5];
    const float* Wv    = (const float*)d_in[6];
    float* out = (float*)d_out;

    __bf16* wpack = (__bf16*)d_ws;
    __bf16* qws = wpack + WS_Q;
    __bf16* kws = wpack + WS_K;
    __bf16* vtws = wpack + WS_VT;

    wconv_kernel<<<1536, 256, 0, stream>>>(Wq, Wk, Wv, wpack);
    proj_kernel<<<dim3(128, 3), 256, 0, stream>>>(query, key, value, wpack, qws, kws, vtws);
    flash_kernel<<<256, 256, 0, stream>>>(qws, kws, vtws, mask, out);
}

// Round 2
// 414.268 us; speedup vs baseline: 1.0200x; 1.0200x over previous
//
#include <hip/hip_runtime.h>
#include <hip/hip_bf16.h>

// B=8, S=2048, DMODEL=1024, DK=128
#define SEQ 2048
#define DMODEL 1024
#define DK 128

typedef __bf16 bf16x8 __attribute__((ext_vector_type(8)));
typedef float  f32x4  __attribute__((ext_vector_type(4)));

#define L2E 1.44269504088896340736f

// ---------------- workspace element offsets (bf16 elements) ----------------
// wpack: [p][hi/lo][128][1024]  -> p*262144 (+131072 for lo)
// q:  [16384][128]  at 786432
// k:  [16384][128]  at 2883584
// vt: [8][128][2048] at 4980736   (end 7077888 bf16 = 14155776 B)
// then fp32 partials: Opart[J][16384][128], ml[J][16384][2]
#define WS_Q  786432
#define WS_K  2883584
#define WS_VT 4980736
#define WS_BF16_BYTES 14155776ull

// ---------------------------------------------------------------------------
// Kernel 1: convert Wq/Wk/Wv fp32 -> split bf16 (hi + lo). Scale folded in Wq.
// ---------------------------------------------------------------------------
__global__ __launch_bounds__(256) void wconv_kernel(
    const float* __restrict__ wq, const float* __restrict__ wk,
    const float* __restrict__ wv, __bf16* __restrict__ wpack)
{
    int i = blockIdx.x * 256 + threadIdx.x;     // 0 .. 393215
    int p = i >> 17;                            // 131072 = 2^17 elems per W
    int j = i & 131071;
    const float* src = (p == 0) ? wq : ((p == 1) ? wk : wv);
    float f = src[j];
    if (p == 0) f *= 0.08838834764831845f;      // 1/sqrt(128) folded into Wq
    __bf16 h = (__bf16)f;
    __bf16 l = (__bf16)(f - (float)h);
    wpack[p * 262144 + j]          = h;
    wpack[p * 262144 + 131072 + j] = l;
}

// ---------------------------------------------------------------------------
// Kernel 2: projection GEMM.  out[m][n] = sum_k x[m][k] * W[n][k]
// x -> plain bf16 (cheap cvt); W split (wh, wl): acc += xh*wh + xh*wl.
// Block: 64 rows x 128 cols, 4 waves (16 rows each). grid 768 -> 3 blocks/CU.
// A loaded global->regs; W hi/lo staged in LDS (pad +8 -> bank-uniform b128).
// p=0 -> q[s][d], p=1 -> k[s][d], p=2 -> v stored transposed vt[d][s].
// ---------------------------------------------------------------------------
__global__ __launch_bounds__(256) void proj_kernel(
    const float* __restrict__ xq, const float* __restrict__ xk,
    const float* __restrict__ xv, const __bf16* __restrict__ wpack,
    __bf16* __restrict__ qws, __bf16* __restrict__ kws, __bf16* __restrict__ vtws)
{
    const int p = blockIdx.y;
    const float* __restrict__ x = (p == 0) ? xq : ((p == 1) ? xk : xv);
    const __bf16* __restrict__ whi_g = wpack + p * 262144;
    const __bf16* __restrict__ wlo_g = whi_g + 131072;

    const int mtile = blockIdx.x;               // [0,256)
    const int m0 = mtile << 6;                  // 64 rows/block
    const int t = threadIdx.x;
    const int wv_ = t >> 6;
    const int lane = t & 63;
    const int l15 = lane & 15, g = lane >> 4;

    // LDS: whi[128][72], wlo[128][72]
    __shared__ __align__(16) __bf16 smem[18432];
    __bf16* whl = smem;
    __bf16* wll = smem + 9216;

    f32x4 acc[8];
#pragma unroll
    for (int nt = 0; nt < 8; ++nt) acc[nt] = (f32x4){0.f, 0.f, 0.f, 0.f};

    for (int kk = 0; kk < 16; ++kk) {           // BK = 64
        __syncthreads();
        // stage W hi/lo tiles: 2 x (128 rows x 64 cols) bf16 = 2048 16B chunks
#pragma unroll
        for (int i = 0; i < 8; ++i) {
            int idx = i * 256 + t;
            int h = idx >> 10, rem = idx & 1023;
            int row = rem >> 3, ck = rem & 7;
            const __bf16* src = (h ? wlo_g : whi_g) + row * 1024 + kk * 64 + ck * 8;
            __bf16* dst = (h ? wll : whl) + row * 72 + ck * 8;
            *(bf16x8*)dst = *(const bf16x8*)src;
        }
        __syncthreads();

#pragma unroll
        for (int ks = 0; ks < 2; ++ks) {
            int row = m0 + wv_ * 16 + l15;
            int col = kk * 64 + ks * 32 + g * 8;
            const float* xp = x + (size_t)row * 1024 + col;
            f32x4 a0 = *(const f32x4*)xp;
            f32x4 a1 = *(const f32x4*)(xp + 4);
            bf16x8 ah;
#pragma unroll
            for (int j = 0; j < 4; ++j) {
                ah[j] = (__bf16)a0[j];
                ah[4 + j] = (__bf16)a1[j];
            }
#pragma unroll
            for (int nt = 0; nt < 8; ++nt) {
                const __bf16* bp = whl + (nt * 16 + l15) * 72 + ks * 32 + g * 8;
                bf16x8 bh = *(const bf16x8*)bp;
                bf16x8 bl = *(const bf16x8*)(bp + 9216);
                acc[nt] = __builtin_amdgcn_mfma_f32_16x16x32_bf16(ah, bh, acc[nt], 0, 0, 0);
                acc[nt] = __builtin_amdgcn_mfma_f32_16x16x32_bf16(ah, bl, acc[nt], 0, 0, 0);
            }
        }
    }

    // epilogue: C frags -> LDS (transposed for p==2) -> coalesced bf16x8 stores
    __syncthreads();
    __bf16* olds = smem;                        // p<2: [64][136]; p==2: [128][72]
#pragma unroll
    for (int nt = 0; nt < 8; ++nt)
#pragma unroll
        for (int r = 0; r < 4; ++r) {
            int rowl = wv_ * 16 + g * 4 + r;    // C row = (lane>>4)*4 + reg
            int col = nt * 16 + l15;            // C col = lane&15
            __bf16 v = (__bf16)acc[nt][r];
            if (p < 2) olds[rowl * 136 + col] = v;
            else       olds[col * 72 + rowl] = v;       // transpose for vt
        }
    __syncthreads();

    const int bq = mtile >> 5, s0 = (mtile & 31) << 6;
    if (p < 2) {
#pragma unroll
        for (int i = 0; i < 4; ++i) {
            int idx = i * 256 + t;
            int row = idx >> 4, ck = idx & 15;          // 64 rows x 16 chunks
            bf16x8 v = *(const bf16x8*)(olds + row * 136 + ck * 8);
            __bf16* dst = ((p == 0) ? qws : kws) + (size_t)(m0 + row) * 128 + ck * 8;
            *(bf16x8*)dst = v;
        }
    } else {
#pragma unroll
        for (int i = 0; i < 4; ++i) {
            int idx = i * 256 + t;
            int row = idx >> 3, ck = idx & 7;           // 128 d-rows x 8 chunks
            bf16x8 v = *(const bf16x8*)(olds + row * 72 + ck * 8);
            __bf16* dst = vtws + ((size_t)(bq * 128 + row)) * 2048 + s0 + ck * 8;
            *(bf16x8*)dst = v;
        }
    }
}

// ---------------------------------------------------------------------------
// Kernel 3: flash attention with runtime K-split (flash-decoding).
// BLOCK_M=64 (4 waves x 16 rows), BLOCK_N=64.  grid = 256 * nsplit.
// nsplit==1: write normalized out.  nsplit>1: write unnormalized O + (m,l).
// ---------------------------------------------------------------------------
__global__ __launch_bounds__(256) void flash_kernel(
    const __bf16* __restrict__ qws, const __bf16* __restrict__ kws,
    const __bf16* __restrict__ vtws, const int* __restrict__ mask,
    float* __restrict__ out, float* __restrict__ part, float* __restrict__ mlbuf,
    int ktp)                                    // K-tiles per split (32/nsplit)
{
    const int bb = blockIdx.x & 7;
    const int rest = blockIdx.x >> 3;
    const int mtile = rest & 31;
    const int jsplit = rest >> 5;
    const int sq0 = mtile << 6;
    const int t = threadIdx.x;
    const int wv_ = t >> 6;
    const int lane = t & 63;
    const int l15 = lane & 15, g = lane >> 4;

    // LDS: k[64][136] (8704) | vt[128][72] (9216) | p[4 waves][16][72] (4608)
    __shared__ __align__(16) __bf16 smem[22528];
    __bf16* klds = smem;
    __bf16* vtlds = smem + 8704;
    __bf16* plds = smem + 17920 + wv_ * 1152;   // wave-private

    // Q fragments (A-layout, registers, pre-scaled by 1/sqrt(dk) via Wq)
    bf16x8 qf[4];
    {
        const __bf16* qp = qws + ((size_t)(bb * 2048 + sq0 + wv_ * 16 + l15)) * 128 + g * 8;
#pragma unroll
        for (int ks = 0; ks < 4; ++ks) qf[ks] = *(const bf16x8*)(qp + ks * 32);
    }

    f32x4 o[8];
#pragma unroll
    for (int nt = 0; nt < 8; ++nt) o[nt] = (f32x4){0.f, 0.f, 0.f, 0.f};
    float m_run[4], l_run[4];
#pragma unroll
    for (int r = 0; r < 4; ++r) { m_run[r] = -__builtin_inff(); l_run[r] = 0.f; }

    const int* mbase = mask + ((size_t)(bb * 2048 + sq0 + wv_ * 16 + g * 4)) * 2048 + l15;

    const int kt_begin = jsplit * ktp, kt_end = kt_begin + ktp;
    for (int kt = kt_begin; kt < kt_end; ++kt) {
        const int n0 = kt << 6;
        __syncthreads();
        // stage K tile [64][128] and Vt tile [128][64] (bf16, padded rows)
#pragma unroll
        for (int i = 0; i < 8; ++i) {
            int idx = i * 256 + t;
            if (idx < 1024) {
                int row = idx >> 4, ck = idx & 15;
                *(bf16x8*)(klds + row * 136 + ck * 8) =
                    *(const bf16x8*)(kws + ((size_t)(bb * 2048 + n0 + row)) * 128 + ck * 8);
            } else {
                int v = idx - 1024;
                int row = v >> 3, ck = v & 7;
                *(bf16x8*)(vtlds + row * 72 + ck * 8) =
                    *(const bf16x8*)(vtws + ((size_t)(bb * 128 + row)) * 2048 + n0 + ck * 8);
            }
        }
        __syncthreads();

        // mask prefetch (in flight during QK MFMAs)
        int mv[4][4];
#pragma unroll
        for (int nt = 0; nt < 4; ++nt)
#pragma unroll
            for (int r = 0; r < 4; ++r)
                mv[nt][r] = mbase[(size_t)r * 2048 + n0 + nt * 16];

        // S = Q K^T  (pre-scaled)
        f32x4 sf[4];
#pragma unroll
        for (int nt = 0; nt < 4; ++nt) sf[nt] = (f32x4){0.f, 0.f, 0.f, 0.f};
#pragma unroll
        for (int nt = 0; nt < 4; ++nt) {
            const __bf16* kp = klds + (nt * 16 + l15) * 136 + g * 8;
#pragma unroll
            for (int ks = 0; ks < 4; ++ks) {
                bf16x8 bfk = *(const bf16x8*)(kp + ks * 32);
                sf[nt] = __builtin_amdgcn_mfma_f32_16x16x32_bf16(qf[ks], bfk, sf[nt], 0, 0, 0);
            }
        }

        // online softmax (rows: g*4+r, reduce across the 16 l15 lanes)
        float mx[4], mnew[4], alpha[4], psum[4];
#pragma unroll
        for (int r = 0; r < 4; ++r)
            mx[r] = fmaxf(fmaxf(sf[0][r], sf[1][r]), fmaxf(sf[2][r], sf[3][r]));
#pragma unroll
        for (int off = 1; off < 16; off <<= 1)
#pragma unroll
            for (int r = 0; r < 4; ++r)
                mx[r] = fmaxf(mx[r], __shfl_xor(mx[r], off, 64));
#pragma unroll
        for (int r = 0; r < 4; ++r) {
            mnew[r] = fmaxf(m_run[r], mx[r]);
            alpha[r] = exp2f((m_run[r] - mnew[r]) * L2E);
            psum[r] = 0.f;
        }
#pragma unroll
        for (int nt = 0; nt < 4; ++nt)
#pragma unroll
            for (int r = 0; r < 4; ++r) {
                float pv = exp2f((sf[nt][r] - mnew[r]) * L2E);
                pv = mv[nt][r] ? pv : 0.f;               // mask after exp: exact
                psum[r] += pv;
                plds[(g * 4 + r) * 72 + nt * 16 + l15] = (__bf16)pv;
            }
#pragma unroll
        for (int off = 1; off < 16; off <<= 1)
#pragma unroll
            for (int r = 0; r < 4; ++r)
                psum[r] += __shfl_xor(psum[r], off, 64);
#pragma unroll
        for (int r = 0; r < 4; ++r) {
            l_run[r] = l_run[r] * alpha[r] + psum[r];
            m_run[r] = mnew[r];
        }
#pragma unroll
        for (int nt = 0; nt < 8; ++nt)
#pragma unroll
            for (int r = 0; r < 4; ++r) o[nt][r] *= alpha[r];

        // P: C-layout -> A-layout via wave-private LDS
        bf16x8 pa[2];
#pragma unroll
        for (int ks2 = 0; ks2 < 2; ++ks2)
            pa[ks2] = *(const bf16x8*)(plds + l15 * 72 + ks2 * 32 + g * 8);

        // O += P V
#pragma unroll
        for (int nt2 = 0; nt2 < 8; ++nt2) {
            const __bf16* vp = vtlds + (nt2 * 16 + l15) * 72 + g * 8;
#pragma unroll
            for (int ks2 = 0; ks2 < 2; ++ks2) {
                bf16x8 bfv = *(const bf16x8*)(vp + ks2 * 32);
                o[nt2] = __builtin_amdgcn_mfma_f32_16x16x32_bf16(pa[ks2], bfv, o[nt2], 0, 0, 0);
            }
        }
    }

    if (part == nullptr) {
        // single-split: normalize + store fp32
        float inv[4];
#pragma unroll
        for (int r = 0; r < 4; ++r) inv[r] = 1.0f / l_run[r];
#pragma unroll
        for (int nt2 = 0; nt2 < 8; ++nt2)
#pragma unroll
            for (int r = 0; r < 4; ++r)
                out[((size_t)(bb * 2048 + sq0 + wv_ * 16 + g * 4 + r)) * 128 + nt2 * 16 + l15] =
                    o[nt2][r] * inv[r];
    } else {
        // write unnormalized partial O + per-row (m, l)
#pragma unroll
        for (int nt2 = 0; nt2 < 8; ++nt2)
#pragma unroll
            for (int r = 0; r < 4; ++r) {
                size_t rowg = (size_t)(bb * 2048 + sq0 + wv_ * 16 + g * 4 + r);
                part[((size_t)jsplit * 16384 + rowg) * 128 + nt2 * 16 + l15] = o[nt2][r];
            }
        if (l15 == 0) {
#pragma unroll
            for (int r = 0; r < 4; ++r) {
                size_t rowg = (size_t)(bb * 2048 + sq0 + wv_ * 16 + g * 4 + r);
                mlbuf[((size_t)jsplit * 16384 + rowg) * 2]     = m_run[r];
                mlbuf[((size_t)jsplit * 16384 + rowg) * 2 + 1] = l_run[r];
            }
        }
    }
}

// ---------------------------------------------------------------------------
// Kernel 4: merge K-split partials.  out = (sum_j e^{m_j-m} O_j) / sum_j e^{m_j-m} l_j
// Block 256 = 8 rows x 32 lanes x f32x4.  grid 2048.
// ---------------------------------------------------------------------------
__global__ __launch_bounds__(256) void merge_kernel(
    const float* __restrict__ part, const float* __restrict__ mlbuf,
    float* __restrict__ out, int J)
{
    int t = threadIdx.x;
    size_t row = (size_t)blockIdx.x * 8 + (t >> 5);
    int c = (t & 31) * 4;
    float mj[4];
    float m = -__builtin_inff();
    for (int j = 0; j < J; ++j) {
        mj[j] = mlbuf[((size_t)j * 16384 + row) * 2];
        m = fmaxf(m, mj[j]);
    }
    float l = 0.f;
    f32x4 acc = (f32x4){0.f, 0.f, 0.f, 0.f};
    for (int j = 0; j < J; ++j) {
        float w = exp2f((mj[j] - m) * L2E);
        l += w * mlbuf[((size_t)j * 16384 + row) * 2 + 1];
        f32x4 v = *(const f32x4*)(part + ((size_t)j * 16384 + row) * 128 + c);
#pragma unroll
        for (int e = 0; e < 4; ++e) acc[e] += w * v[e];
    }
    float inv = 1.0f / l;
#pragma unroll
    for (int e = 0; e < 4; ++e) acc[e] *= inv;
    *(f32x4*)(out + row * 128 + c) = acc;
}

// ---------------------------------------------------------------------------
extern "C" void kernel_launch(void* const* d_in, const int* in_sizes, int n_in,
                              void* d_out, int out_size, void* d_ws, size_t ws_size,
                              hipStream_t stream)
{
    const float* query = (const float*)d_in[0];
    const float* key   = (const float*)d_in[1];
    const float* value = (const float*)d_in[2];
    const int*   mask  = (const int*)d_in[3];
    const float* Wq    = (const float*)d_in[4];
    const float* Wk    = (const float*)d_in[5];
    const float* Wv    = (const float*)d_in[6];
    float* out = (float*)d_out;

    __bf16* wpack = (__bf16*)d_ws;
    __bf16* qws = wpack + WS_Q;
    __bf16* kws = wpack + WS_K;
    __bf16* vtws = wpack + WS_VT;

    // choose K-split from workspace budget: per split 16384*128*4 + 16384*8 B
    const size_t per_split = 16384ull * 128 * 4 + 16384ull * 8;  // 8519680
    int J = 1;
    if (ws_size >= WS_BF16_BYTES + 4 * per_split)      J = 4;
    else if (ws_size >= WS_BF16_BYTES + 2 * per_split) J = 2;
    float* part = (J > 1) ? (float*)((char*)d_ws + WS_BF16_BYTES) : nullptr;
    float* mlbuf = (J > 1) ? (part + (size_t)J * 16384 * 128) : nullptr;

    wconv_kernel<<<1536, 256, 0, stream>>>(Wq, Wk, Wv, wpack);
    proj_kernel<<<dim3(256, 3), 256, 0, stream>>>(query, key, value, wpack, qws, kws, vtws);
    flash_kernel<<<256 * J, 256, 0, stream>>>(qws, kws, vtws, mask, out, part, mlbuf, 32 / J);
    if (J > 1) merge_kernel<<<2048, 256, 0, stream>>>(part, mlbuf, out, J);
}